// Round 3
// baseline (204.207 us; speedup 1.0000x reference)
//
#include <hip/hip_runtime.h>

#define VOCAB 40
#define SEQ 128
#define THREADS 256
#define ROWS_PER_BLOCK (THREADS / 2)  // 2 threads per row
#define HW 21  // 10 A-words + 10 B-words + 1 pad; odd stride -> conflict-free

__global__ __launch_bounds__(THREADS) void char_dist_kernel(
    const int* __restrict__ x, float* __restrict__ out, int batch) {
  __shared__ unsigned int hist[THREADS * HW];
  const int tid = threadIdx.x;
  const int row = blockIdx.x * ROWS_PER_BLOCK + (tid >> 1);
  const int half = tid & 1;
  const bool active = row < batch;

  unsigned int* h = &hist[tid * HW];
#pragma unroll
  for (int w = 0; w < 20; ++w) h[w] = 0u;

  if (active) {
    // this thread handles 64 tokens = 16 int4 chunks
    const int4* rowp = reinterpret_cast<const int4*>(x) +
                       ((long)row * (SEQ / 4) + half * (SEQ / 8));
    int4 c0 = rowp[0], c1 = rowp[1], c2 = rowp[2], c3 = rowp[3];
#pragma unroll
    for (int j = 0; j < 16; j += 4) {
      int4 n0 = c0, n1 = c1, n2 = c2, n3 = c3;
      if (j + 4 < 16) {
        n0 = rowp[j + 4];
        n1 = rowp[j + 5];
        n2 = rowp[j + 6];
        n3 = rowp[j + 7];
      }
      // A-chain (words 0..9): tokens x,z ; B-chain (words 10..19): tokens y,w
      h[c0.x >> 2] += 1u << ((c0.x & 3) << 3);
      h[10 + (c0.y >> 2)] += 1u << ((c0.y & 3) << 3);
      h[c0.z >> 2] += 1u << ((c0.z & 3) << 3);
      h[10 + (c0.w >> 2)] += 1u << ((c0.w & 3) << 3);

      h[c1.x >> 2] += 1u << ((c1.x & 3) << 3);
      h[10 + (c1.y >> 2)] += 1u << ((c1.y & 3) << 3);
      h[c1.z >> 2] += 1u << ((c1.z & 3) << 3);
      h[10 + (c1.w >> 2)] += 1u << ((c1.w & 3) << 3);

      h[c2.x >> 2] += 1u << ((c2.x & 3) << 3);
      h[10 + (c2.y >> 2)] += 1u << ((c2.y & 3) << 3);
      h[c2.z >> 2] += 1u << ((c2.z & 3) << 3);
      h[10 + (c2.w >> 2)] += 1u << ((c2.w & 3) << 3);

      h[c3.x >> 2] += 1u << ((c3.x & 3) << 3);
      h[10 + (c3.y >> 2)] += 1u << ((c3.y & 3) << 3);
      h[c3.z >> 2] += 1u << ((c3.z & 3) << 3);
      h[10 + (c3.w >> 2)] += 1u << ((c3.w & 3) << 3);

      c0 = n0; c1 = n1; c2 = n2; c3 = n3;
    }
  }
  __syncthreads();

  // Merge the pair's 4 sub-histograms word-wise (byte lanes can't overflow:
  // per-bin row count <= 128 < 256) and extract features; even thread takes
  // words 0..4 (bins 0..19), odd thread words 5..9 (bins 20..39).
  const unsigned int* hp = &hist[(tid ^ 1) * HW];
  int total = 0, uniq = 0, maxc = 0, minc = 0x7fffffff;
  int letters = 0, digits = 0, special = 0;
  const int wbase = half * 5;
#pragma unroll
  for (int k = 0; k < 5; ++k) {
    const int w = wbase + k;
    const unsigned int m = h[w] + h[10 + w] + hp[w] + hp[10 + w];
#pragma unroll
    for (int b = 0; b < 4; ++b) {
      const int bin = w * 4 + b;
      const int c = (int)((m >> (b * 8)) & 0xFFu);
      if (bin != 0) {  // bin 0 is padding, excluded from all stats
        total += c;
        uniq += (c > 0) ? 1 : 0;
        maxc = max(maxc, c);
        if (c > 0) minc = min(minc, c);
        if (bin <= 26) letters += c;
        else if (bin <= 36) digits += c;
        else special += c;
      }
    }
  }

  // Combine the two half-row partials within the lane pair.
  total   += __shfl_xor(total, 1);
  uniq    += __shfl_xor(uniq, 1);
  letters += __shfl_xor(letters, 1);
  digits  += __shfl_xor(digits, 1);
  special += __shfl_xor(special, 1);
  maxc = max(maxc, __shfl_xor(maxc, 1));
  minc = min(minc, __shfl_xor(minc, 1));

  if (active) {
    if (minc == 0x7fffffff) minc = 0;  // empty row
    const float inv = 1.0f / (float)max(total, 1);
    const float f0 = (float)uniq * (1.0f / (float)VOCAB);
    const float f1 = (float)maxc * inv;
    const float f2 = (float)minc * inv;
    const float f3 = (float)letters * inv;
    const float f4 = (float)digits * inv;
    const float f5 = (float)special * inv;
    float2* o = reinterpret_cast<float2*>(out + (long)row * 6);
    if (half == 0) {
      o[0] = make_float2(f0, f1);
      o[1] = make_float2(f2, f3);
    } else {
      o[2] = make_float2(f4, f5);
    }
  }
}

extern "C" void kernel_launch(void* const* d_in, const int* in_sizes, int n_in,
                              void* d_out, int out_size, void* d_ws, size_t ws_size,
                              hipStream_t stream) {
  const int* x = (const int*)d_in[0];
  float* out = (float*)d_out;
  const int batch = in_sizes[0] / SEQ;
  const int blocks = (batch + ROWS_PER_BLOCK - 1) / ROWS_PER_BLOCK;
  char_dist_kernel<<<blocks, THREADS, 0, stream>>>(x, out, batch);
}